// Round 13
// baseline (4075.461 us; speedup 1.0000x reference)
//
#include <hip/hip_runtime.h>
#include <hip/hip_bf16.h>
#include <hip/hip_fp16.h>
#include <cstddef>
#include <cstdint>

#define HDIM 512
#define NNODES 1024
#define NEDGES 16384
#define BATCH 32
#define SEQ 1024
#define DIN 128
#define RING 8

#define RLX __ATOMIC_RELAXED
#define AGT __HIP_MEMORY_SCOPE_AGENT

// ---------------------------------------------------------------------------
// Prologue: AWp[d][j] = sum_{e: dst_e=d} Wp[src_e][j]
// ---------------------------------------------------------------------------
__global__ void scatter_awp_kernel(const float* __restrict__ Wp,
                                   const int* __restrict__ src,
                                   const int* __restrict__ dst,
                                   float* __restrict__ AWp) {
    int e = blockIdx.x;
    int c = threadIdx.x;
    int s = src[e], d = dst[e];
    atomicAdd(&AWp[d * HDIM + c],       Wp[s * HDIM + c]);
    atomicAdd(&AWp[d * HDIM + 256 + c], Wp[s * HDIM + 256 + c]);
}

__global__ void scatter_abp_kernel(const float* __restrict__ bp,
                                   const int* __restrict__ src,
                                   const int* __restrict__ dst,
                                   float* __restrict__ Abp) {
    int e = blockIdx.x * blockDim.x + threadIdx.x;
    if (e < NEDGES) atomicAdd(&Abp[dst[e]], bp[src[e]]);
}

__global__ void beff_kernel(const float* __restrict__ Wu,
                            const float* __restrict__ Abp,
                            const float* __restrict__ bias,
                            const float* __restrict__ bu,
                            float* __restrict__ beff) {
    int i = threadIdx.x;
    float s = 0.f;
    for (int d = 0; d < NNODES; ++d) s += Wu[i * NNODES + d] * Abp[d];
    beff[i] = bias[i] + bu[i] + s;
}

__global__ void tof16_kernel(const float* __restrict__ in,
                             __half* __restrict__ out, int n) {
    int i = blockIdx.x * blockDim.x + threadIdx.x;
    if (i < n) out[i] = __float2half_rn(in[i]);
}

// ---------------------------------------------------------------------------
// fp32 tiled GEMM (prologue): C = A @ B (+addend); TB==1 -> B is (N x K)
// ---------------------------------------------------------------------------
template <int TB>
__global__ __launch_bounds__(256) void gemm64(const float* __restrict__ A,
                                              const float* __restrict__ B,
                                              float* __restrict__ C,
                                              const float* __restrict__ addend,
                                              int M, int N, int K) {
    const int bn = blockIdx.x, bm = blockIdx.y;
    const int tid = threadIdx.x;
    const int tx = tid & 15, ty = tid >> 4;
    const int m0 = bm * 64, n0 = bn * 64;

    __shared__ float As[16][68];
    __shared__ float Bs[16][68];

    float acc[4][4] = {};

    for (int k0 = 0; k0 < K; k0 += 16) {
        {
            int kk = tid & 15, m = tid >> 4;
            #pragma unroll
            for (int i = 0; i < 4; ++i)
                As[kk][m + 16 * i] = A[(size_t)(m0 + m + 16 * i) * K + k0 + kk];
        }
        if (TB == 0) {
            int n = tid & 63, kk = tid >> 6;
            #pragma unroll
            for (int i = 0; i < 4; ++i)
                Bs[kk + 4 * i][n] = B[(size_t)(k0 + kk + 4 * i) * N + n0 + n];
        } else {
            int kk = tid & 15, n = tid >> 4;
            #pragma unroll
            for (int i = 0; i < 4; ++i)
                Bs[kk][n + 16 * i] = B[(size_t)(n0 + n + 16 * i) * K + k0 + kk];
        }
        __syncthreads();
        #pragma unroll
        for (int kk = 0; kk < 16; ++kk) {
            float4 a4 = *reinterpret_cast<const float4*>(&As[kk][ty * 4]);
            float4 b4 = *reinterpret_cast<const float4*>(&Bs[kk][tx * 4]);
            float av[4] = {a4.x, a4.y, a4.z, a4.w};
            float bv[4] = {b4.x, b4.y, b4.z, b4.w};
            #pragma unroll
            for (int i = 0; i < 4; ++i)
                #pragma unroll
                for (int j = 0; j < 4; ++j)
                    acc[i][j] += av[i] * bv[j];
        }
        __syncthreads();
    }
    #pragma unroll
    for (int i = 0; i < 4; ++i) {
        int m = m0 + ty * 4 + i;
        #pragma unroll
        for (int j = 0; j < 4; ++j) {
            int n = n0 + tx * 4 + j;
            float v = acc[i][j];
            if (addend) v += addend[(size_t)m * N + n];
            C[(size_t)m * N + n] = v;
        }
    }
}

// ---------------------------------------------------------------------------
// DPP half-wave sum (R5-verified): lanes 31/63 hold their 32-lane half sums.
// ---------------------------------------------------------------------------
template <int CTRL, int RMASK, bool BC>
__device__ __forceinline__ float dpp_add(float x) {
    int t = __builtin_amdgcn_update_dpp(0, __float_as_int(x), CTRL, RMASK, 0xf, BC);
    return x + __int_as_float(t);
}

__device__ __forceinline__ float reduce32(float x) {
    x = dpp_add<0x111, 0xf, true>(x);
    x = dpp_add<0x112, 0xf, true>(x);
    x = dpp_add<0x114, 0xf, true>(x);
    x = dpp_add<0x118, 0xf, true>(x);
    x = dpp_add<0x142, 0xa, false>(x);
    return x;
}

__device__ __forceinline__ float fast_tanh(float x) {
    float e = __expf(2.0f * x);
    return 1.0f - 2.0f / (e + 1.0f);
}

// ---------------------------------------------------------------------------
// Split dual-layer scan: 512 WGs (2/CU), grid (8 slices, 32 batch, 2 layers).
// z==0 (L0): R5 skeleton; Weff0 slice fp16 in LDS (64KB). Publishes h0 into a
//   DEPTH-8 tagged ring (slot i&7 holds tag i). No out/u1 work at all.
//   Gate: before storing tag i+1 it requires min_s prog1[b][s] >= i-7 so no
//   L1 consumer can still need the slot being overwritten. L0-peer safety is
//   by induction: producer polled tag i from all peers => every peer finished
//   iteration i-1 => consumed the ring slot's old tag (<= i-7) long ago.
// z==1 (L1): polls h0(j) from the ring (L0 runs ahead -> usually instant) and
//   h1(j-1) from parity slots (own 8-WG lockstep chain, R3-proven induction);
//   g = Win1(streamed fp16, 64KB/step).h0 + Weff1(fp16 LDS).h1; writes ys1.
//   Publishes prog1[b][slice]=j after the barrier (all threads' h0 reads of
//   slot j&7 complete) -- exactly what the L0 gate needs.
// Throttling: L0 matches L1's rate with 8 steps of slack; tau ~= the single-
// layer h1 chain (~R3's 1.9-2.3us), streaming cut to 16MB/step device-wide.
// ---------------------------------------------------------------------------
__launch_bounds__(512, 4)
__global__ void scan_split_kernel(const float* __restrict__ Weff0,
                                  const float* __restrict__ beff0,
                                  const float* __restrict__ Weff1,
                                  const float* __restrict__ beff1,
                                  const __half* __restrict__ Win1h, // fp16 [H][H]
                                  const float* __restrict__ u0,     // (B,S,H)
                                  float* __restrict__ out,          // (B,S,H) ys1
                                  unsigned long long* __restrict__ hp0, // [RING][B][H]
                                  unsigned long long* __restrict__ hp1, // [2][B][H]
                                  unsigned* __restrict__ prog1) {       // [B*8]
    const int slice = blockIdx.x;   // 0..7
    const int b = blockIdx.y;       // 0..31
    const int tid = threadIdx.x;    // 0..511
    const int c = tid & 31;
    const int hw = tid >> 5;        // 0..15
    const int rloc = hw * 4;
    const int rowbase = slice * 64 + rloc;
    const bool storer = (c == 31);
    const size_t SLOTS = (size_t)BATCH * HDIM;

    __shared__ __align__(16) unsigned char smembuf[73728];

    if (blockIdx.z == 0) {
        // ========================= layer 0 =========================
        __half* wl = (__half*)smembuf;                       // 64 KB
        float (*hs)[HDIM] = (float(*)[HDIM])(smembuf + 65536); // 4 KB

        // preload + convert Weff0 slice -> fp16 LDS
        {
            const float4* src4 = reinterpret_cast<const float4*>(
                Weff0 + (size_t)slice * 64 * HDIM);
            __half2* dst2 = reinterpret_cast<__half2*>(wl);
            #pragma unroll
            for (int i = 0; i < 16; ++i) {
                float4 v = src4[tid + 512 * i];
                dst2[2 * (tid + 512 * i)]     = __floats2half2_rn(v.x, v.y);
                dst2[2 * (tid + 512 * i) + 1] = __floats2half2_rn(v.z, v.w);
            }
        }
        float4 be4 = make_float4(0.f, 0.f, 0.f, 0.f);
        if (storer) be4 = *reinterpret_cast<const float4*>(beff0 + rowbase);
        const float lk = 0.10f, olk = 0.90f;
        const float* ub = u0 + (size_t)b * SEQ * HDIM;
        float4 hold = make_float4(0.f, 0.f, 0.f, 0.f);
        __syncthreads();

        for (int i = 0; i < SEQ; ++i) {
            float4 u4 = make_float4(0.f, 0.f, 0.f, 0.f);
            if (storer)
                u4 = *reinterpret_cast<const float4*>(ub + (size_t)i * HDIM + rowbase);

            // ring-overwrite gate (8 steps in arrears; no spin in steady state)
            if (i >= RING && tid < 8) {
                while ((int)__hip_atomic_load(&prog1[b * 8 + tid], RLX, AGT) < i - (RING - 1)) {}
            }

            // poll h0(i) from ring slot i&7
            const unsigned long long* sp = hp0 + (size_t)(i & (RING - 1)) * SLOTS
                                         + (size_t)b * HDIM + tid;
            unsigned long long v = __hip_atomic_load(sp, RLX, AGT);
            while ((unsigned)(v >> 32) != (unsigned)i)
                v = __hip_atomic_load(sp, RLX, AGT);
            hs[i & 1][tid] = __uint_as_float((unsigned)v);
            __syncthreads();

            float a0 = 0.f, a1 = 0.f, a2 = 0.f, a3 = 0.f;
            const float* hv = hs[i & 1];
            #pragma unroll
            for (int k = 0; k < 4; ++k) {
                const int co = 4 * (c + 32 * k);
                float4 h4 = *reinterpret_cast<const float4*>(hv + co);
                #pragma unroll
                for (int r = 0; r < 4; ++r) {
                    __half2 p = *reinterpret_cast<const __half2*>(&wl[(rloc + r) * HDIM + co]);
                    __half2 q = *reinterpret_cast<const __half2*>(&wl[(rloc + r) * HDIM + co + 2]);
                    float2 pf = __half22float2(p);
                    float2 qf = __half22float2(q);
                    float acc = pf.x * h4.x + pf.y * h4.y + qf.x * h4.z + qf.y * h4.w;
                    if (r == 0) a0 += acc;
                    else if (r == 1) a1 += acc;
                    else if (r == 2) a2 += acc;
                    else a3 += acc;
                }
            }
            a0 = reduce32(a0);
            a1 = reduce32(a1);
            a2 = reduce32(a2);
            a3 = reduce32(a3);

            if (storer) {
                float n0 = olk * hold.x + lk * fast_tanh(a0 + u4.x + be4.x);
                float n1 = olk * hold.y + lk * fast_tanh(a1 + u4.y + be4.y);
                float n2 = olk * hold.z + lk * fast_tanh(a2 + u4.z + be4.z);
                float n3 = olk * hold.w + lk * fast_tanh(a3 + u4.w + be4.w);
                hold = make_float4(n0, n1, n2, n3);
                unsigned long long tg = ((unsigned long long)(unsigned)(i + 1)) << 32;
                unsigned long long* hp = hp0 + (size_t)((i + 1) & (RING - 1)) * SLOTS
                                       + (size_t)b * HDIM + rowbase;
                __hip_atomic_store(hp + 0, tg | __float_as_uint(n0), RLX, AGT);
                __hip_atomic_store(hp + 1, tg | __float_as_uint(n1), RLX, AGT);
                __hip_atomic_store(hp + 2, tg | __float_as_uint(n2), RLX, AGT);
                __hip_atomic_store(hp + 3, tg | __float_as_uint(n3), RLX, AGT);
            }
        }
    } else {
        // ========================= layer 1 =========================
        __half* wl1 = (__half*)smembuf;                        // 64 KB Weff1
        float (*hs0)[HDIM] = (float(*)[HDIM])(smembuf + 65536);  // 4 KB
        float (*hs1)[HDIM] = (float(*)[HDIM])(smembuf + 69632);  // 4 KB

        // preload + convert Weff1 slice -> fp16 LDS
        {
            const float4* src4 = reinterpret_cast<const float4*>(
                Weff1 + (size_t)slice * 64 * HDIM);
            __half2* dst2 = reinterpret_cast<__half2*>(wl1);
            #pragma unroll
            for (int i = 0; i < 16; ++i) {
                float4 v = src4[tid + 512 * i];
                dst2[2 * (tid + 512 * i)]     = __floats2half2_rn(v.x, v.y);
                dst2[2 * (tid + 512 * i) + 1] = __floats2half2_rn(v.z, v.w);
            }
        }
        float4 be4 = make_float4(0.f, 0.f, 0.f, 0.f);
        if (storer) be4 = *reinterpret_cast<const float4*>(beff1 + rowbase);
        const float lk = 0.15f, olk = 0.85f;
        float* ob = out + (size_t)b * SEQ * HDIM;
        float4 hold = make_float4(0.f, 0.f, 0.f, 0.f);
        __syncthreads();

        for (int j = 1; j <= SEQ; ++j) {
            // stream Win1 rows (fp16, L2-hot) -- issue before polls
            uint2 wi16[4][4];
            #pragma unroll
            for (int r = 0; r < 4; ++r)
                #pragma unroll
                for (int k = 0; k < 4; ++k) {
                    const int co = 4 * (c + 32 * k);
                    wi16[r][k] = *reinterpret_cast<const uint2*>(
                        Win1h + (size_t)(rowbase + r) * HDIM + co);
                }

            // first-try h1(j-1), then poll h0(j) (ring; L0 ahead -> instant)
            const unsigned long long* sp1 = hp1 + (size_t)((j - 1) & 1) * SLOTS
                                          + (size_t)b * HDIM + tid;
            unsigned long long v1 = __hip_atomic_load(sp1, RLX, AGT);
            const unsigned long long* sp0 = hp0 + (size_t)(j & (RING - 1)) * SLOTS
                                          + (size_t)b * HDIM + tid;
            unsigned long long v0 = __hip_atomic_load(sp0, RLX, AGT);
            while ((unsigned)(v0 >> 32) != (unsigned)j)
                v0 = __hip_atomic_load(sp0, RLX, AGT);
            hs0[j & 1][tid] = __uint_as_float((unsigned)v0);
            while ((unsigned)(v1 >> 32) != (unsigned)(j - 1))
                v1 = __hip_atomic_load(sp1, RLX, AGT);
            hs1[(j - 1) & 1][tid] = __uint_as_float((unsigned)v1);
            __syncthreads();
            // all threads' reads of ring slot j&7 are complete -> publish
            if (tid == 0)
                __hip_atomic_store(&prog1[b * 8 + slice], (unsigned)j, RLX, AGT);

            float g0 = 0.f, g1 = 0.f, g2 = 0.f, g3 = 0.f;
            const float* h0v = hs0[j & 1];
            const float* h1v = hs1[(j - 1) & 1];
            #pragma unroll
            for (int k = 0; k < 4; ++k) {
                const int co = 4 * (c + 32 * k);
                float4 p4 = *reinterpret_cast<const float4*>(h0v + co);
                float4 q4 = *reinterpret_cast<const float4*>(h1v + co);
                #pragma unroll
                for (int r = 0; r < 4; ++r) {
                    float2 wa = __half22float2(*reinterpret_cast<const __half2*>(&wi16[r][k].x));
                    float2 wb = __half22float2(*reinterpret_cast<const __half2*>(&wi16[r][k].y));
                    __half2 ea = *reinterpret_cast<const __half2*>(&wl1[(rloc + r) * HDIM + co]);
                    __half2 eb = *reinterpret_cast<const __half2*>(&wl1[(rloc + r) * HDIM + co + 2]);
                    float2 ef = __half22float2(ea);
                    float2 eg = __half22float2(eb);
                    float acc = wa.x * p4.x + wa.y * p4.y + wb.x * p4.z + wb.y * p4.w
                              + ef.x * q4.x + ef.y * q4.y + eg.x * q4.z + eg.y * q4.w;
                    if (r == 0) g0 += acc;
                    else if (r == 1) g1 += acc;
                    else if (r == 2) g2 += acc;
                    else g3 += acc;
                }
            }
            g0 = reduce32(g0);
            g1 = reduce32(g1);
            g2 = reduce32(g2);
            g3 = reduce32(g3);

            if (storer) {
                float m0 = olk * hold.x + lk * fast_tanh(g0 + be4.x);
                float m1 = olk * hold.y + lk * fast_tanh(g1 + be4.y);
                float m2 = olk * hold.z + lk * fast_tanh(g2 + be4.z);
                float m3 = olk * hold.w + lk * fast_tanh(g3 + be4.w);
                hold = make_float4(m0, m1, m2, m3);
                unsigned long long tg = ((unsigned long long)(unsigned)j) << 32;
                unsigned long long* hp = hp1 + (size_t)(j & 1) * SLOTS
                                       + (size_t)b * HDIM + rowbase;
                __hip_atomic_store(hp + 0, tg | __float_as_uint(m0), RLX, AGT);
                __hip_atomic_store(hp + 1, tg | __float_as_uint(m1), RLX, AGT);
                __hip_atomic_store(hp + 2, tg | __float_as_uint(m2), RLX, AGT);
                __hip_atomic_store(hp + 3, tg | __float_as_uint(m3), RLX, AGT);
                *reinterpret_cast<float4*>(ob + (size_t)(j - 1) * HDIM + rowbase) =
                    make_float4(m0, m1, m2, m3);   // ys1
            }
        }
    }
}

// ---------------------------------------------------------------------------
extern "C" void kernel_launch(void* const* d_in, const int* in_sizes, int n_in,
                              void* d_out, int out_size, void* d_ws, size_t ws_size,
                              hipStream_t stream) {
    const float* x      = (const float*)d_in[0];
    const int*   edges  = (const int*)d_in[1];
    const float* W_in0  = (const float*)d_in[2];
    const float* W_res0 = (const float*)d_in[3];
    const float* bias0  = (const float*)d_in[4];
    const float* Wp0    = (const float*)d_in[5];
    const float* bp0    = (const float*)d_in[6];
    const float* Wu0    = (const float*)d_in[7];
    const float* bu0    = (const float*)d_in[8];
    const float* W_in1  = (const float*)d_in[9];
    const float* W_res1 = (const float*)d_in[10];
    const float* bias1  = (const float*)d_in[11];
    const float* Wp1    = (const float*)d_in[12];
    const float* bp1    = (const float*)d_in[13];
    const float* Wu1    = (const float*)d_in[14];
    const float* bu1    = (const float*)d_in[15];

    const int* src = edges;
    const int* dst = edges + NEDGES;
    float* out = (float*)d_out;

    // workspace layout (total 71,311,360 B <= R11's proven 71,835,648)
    char* base = (char*)d_ws;
    float* ws_u = (float*)base;                       // u0: 67,108,864
    char* q = base + (size_t)67108864;
    float* AWp = (float*)q;                           // prologue: 2,097,152
    // post-prologue overlay of AWp's region:
    unsigned long long* hp0 = (unsigned long long*)q;            // 1,048,576
    unsigned long long* hp1 = (unsigned long long*)(q + 1048576);//   262,144
    unsigned* prog1 = (unsigned*)(q + 1310720);                  //     4,096
    __half* Win1h = (__half*)(q + 1314816);                      //   524,288
    char* p2 = q + 2097152;
    float* Abp   = (float*)p2;                        // 4,096
    float* Weff0 = (float*)(p2 + 4096);               // 1,048,576
    float* Weff1 = (float*)(p2 + 1052672);            // 1,048,576
    float* beff0 = (float*)(p2 + 2101248);            // 2,048
    float* beff1 = (float*)(p2 + 2103296);            // 2,048

    // ---- layer 0 effective weights ----
    hipMemsetAsync(AWp, 0, 2097152, stream);
    hipMemsetAsync(Abp, 0, 4096, stream);
    scatter_awp_kernel<<<NEDGES, 256, 0, stream>>>(Wp0, src, dst, AWp);
    scatter_abp_kernel<<<NEDGES / 256, 256, 0, stream>>>(bp0, src, dst, Abp);
    gemm64<0><<<dim3(8, 8), 256, 0, stream>>>(Wu0, AWp, Weff0, W_res0, 512, 512, 1024);
    beff_kernel<<<1, 512, 0, stream>>>(Wu0, Abp, bias0, bu0, beff0);

    // ---- layer 1 effective weights ----
    hipMemsetAsync(AWp, 0, 2097152, stream);
    hipMemsetAsync(Abp, 0, 4096, stream);
    scatter_awp_kernel<<<NEDGES, 256, 0, stream>>>(Wp1, src, dst, AWp);
    scatter_abp_kernel<<<NEDGES / 256, 256, 0, stream>>>(bp1, src, dst, Abp);
    gemm64<0><<<dim3(8, 8), 256, 0, stream>>>(Wu1, AWp, Weff1, W_res1, 512, 512, 1024);
    beff_kernel<<<1, 512, 0, stream>>>(Wu1, Abp, bias1, bu1, beff1);

    // ---- u0 = x @ W_in0^T ----
    gemm64<1><<<dim3(512 / 64, 32768 / 64), 256, 0, stream>>>(
        x, W_in0, ws_u, nullptr, BATCH * SEQ, HDIM, DIN);

    // ---- AWp dead: zero sync structures, build fp16 Win1 ----
    hipMemsetAsync(q, 0, 1314816 + 4096, stream);   // hp0 + hp1 + prog1
    tof16_kernel<<<HDIM * HDIM / 1024, 1024, 0, stream>>>(W_in1, Win1h, HDIM * HDIM);

    // ---- concurrent split dual-layer scan ----
    scan_split_kernel<<<dim3(8, BATCH, 2), 512, 0, stream>>>(
        Weff0, beff0, Weff1, beff1, Win1h, ws_u, out, hp0, hp1, prog1);
}

// Round 14
// 3448.256 us; speedup vs baseline: 1.1819x; 1.1819x over previous
//
#include <hip/hip_runtime.h>
#include <hip/hip_bf16.h>
#include <hip/hip_fp16.h>
#include <cstddef>
#include <cstdint>

#define HDIM 512
#define NNODES 1024
#define NEDGES 16384
#define BATCH 32
#define SEQ 1024
#define DIN 128
#define SLICES 8

#define RLX __ATOMIC_RELAXED
#define AGT __HIP_MEMORY_SCOPE_AGENT

typedef _Float16 h2 __attribute__((ext_vector_type(2)));

// ---------------------------------------------------------------------------
// Prologue: AWp[d][j] = sum_{e: dst_e=d} Wp[src_e][j]
// ---------------------------------------------------------------------------
__global__ void scatter_awp_kernel(const float* __restrict__ Wp,
                                   const int* __restrict__ src,
                                   const int* __restrict__ dst,
                                   float* __restrict__ AWp) {
    int e = blockIdx.x;
    int c = threadIdx.x;
    int s = src[e], d = dst[e];
    atomicAdd(&AWp[d * HDIM + c],       Wp[s * HDIM + c]);
    atomicAdd(&AWp[d * HDIM + 256 + c], Wp[s * HDIM + 256 + c]);
}

__global__ void scatter_abp_kernel(const float* __restrict__ bp,
                                   const int* __restrict__ src,
                                   const int* __restrict__ dst,
                                   float* __restrict__ Abp) {
    int e = blockIdx.x * blockDim.x + threadIdx.x;
    if (e < NEDGES) atomicAdd(&Abp[dst[e]], bp[src[e]]);
}

__global__ void beff_kernel(const float* __restrict__ Wu,
                            const float* __restrict__ Abp,
                            const float* __restrict__ bias,
                            const float* __restrict__ bu,
                            float* __restrict__ beff) {
    int i = threadIdx.x;
    float s = 0.f;
    for (int d = 0; d < NNODES; ++d) s += Wu[i * NNODES + d] * Abp[d];
    beff[i] = bias[i] + bu[i] + s;
}

__global__ void tof16_kernel(const float* __restrict__ in,
                             __half* __restrict__ out, int n) {
    int i = blockIdx.x * blockDim.x + threadIdx.x;
    if (i < n) out[i] = __float2half_rn(in[i]);
}

// ---------------------------------------------------------------------------
// fp32 tiled GEMM (prologue): C = A @ B (+addend); TB==1 -> B is (N x K)
// ---------------------------------------------------------------------------
template <int TB>
__global__ __launch_bounds__(256) void gemm64(const float* __restrict__ A,
                                              const float* __restrict__ B,
                                              float* __restrict__ C,
                                              const float* __restrict__ addend,
                                              int M, int N, int K) {
    const int bn = blockIdx.x, bm = blockIdx.y;
    const int tid = threadIdx.x;
    const int tx = tid & 15, ty = tid >> 4;
    const int m0 = bm * 64, n0 = bn * 64;

    __shared__ float As[16][68];
    __shared__ float Bs[16][68];

    float acc[4][4] = {};

    for (int k0 = 0; k0 < K; k0 += 16) {
        {
            int kk = tid & 15, m = tid >> 4;
            #pragma unroll
            for (int i = 0; i < 4; ++i)
                As[kk][m + 16 * i] = A[(size_t)(m0 + m + 16 * i) * K + k0 + kk];
        }
        if (TB == 0) {
            int n = tid & 63, kk = tid >> 6;
            #pragma unroll
            for (int i = 0; i < 4; ++i)
                Bs[kk + 4 * i][n] = B[(size_t)(k0 + kk + 4 * i) * N + n0 + n];
        } else {
            int kk = tid & 15, n = tid >> 4;
            #pragma unroll
            for (int i = 0; i < 4; ++i)
                Bs[kk][n + 16 * i] = B[(size_t)(n0 + n + 16 * i) * K + k0 + kk];
        }
        __syncthreads();
        #pragma unroll
        for (int kk = 0; kk < 16; ++kk) {
            float4 a4 = *reinterpret_cast<const float4*>(&As[kk][ty * 4]);
            float4 b4 = *reinterpret_cast<const float4*>(&Bs[kk][tx * 4]);
            float av[4] = {a4.x, a4.y, a4.z, a4.w};
            float bv[4] = {b4.x, b4.y, b4.z, b4.w};
            #pragma unroll
            for (int i = 0; i < 4; ++i)
                #pragma unroll
                for (int j = 0; j < 4; ++j)
                    acc[i][j] += av[i] * bv[j];
        }
        __syncthreads();
    }
    #pragma unroll
    for (int i = 0; i < 4; ++i) {
        int m = m0 + ty * 4 + i;
        #pragma unroll
        for (int j = 0; j < 4; ++j) {
            int n = n0 + tx * 4 + j;
            float v = acc[i][j];
            if (addend) v += addend[(size_t)m * N + n];
            C[(size_t)m * N + n] = v;
        }
    }
}

// ---------------------------------------------------------------------------
// DPP half-wave sum (R5-verified): lanes 31/63 hold their 32-lane half sums.
// ---------------------------------------------------------------------------
template <int CTRL, int RMASK, bool BC>
__device__ __forceinline__ float dpp_add(float x) {
    int t = __builtin_amdgcn_update_dpp(0, __float_as_int(x), CTRL, RMASK, 0xf, BC);
    return x + __int_as_float(t);
}

__device__ __forceinline__ float reduce32(float x) {
    x = dpp_add<0x111, 0xf, true>(x);
    x = dpp_add<0x112, 0xf, true>(x);
    x = dpp_add<0x114, 0xf, true>(x);
    x = dpp_add<0x118, 0xf, true>(x);
    x = dpp_add<0x142, 0xa, false>(x);
    return x;
}

__device__ __forceinline__ float fast_tanh(float x) {
    float e = __expf(2.0f * x);
    return 1.0f - 2.0f / (e + 1.0f);
}

// v_dot2_f32_f16: 2 fp16 MACs with fp32 accumulate (fallback: cvt + fma)
__device__ __forceinline__ float fdot2(h2 a, h2 b, float c) {
#if __has_builtin(__builtin_amdgcn_fdot2)
    return __builtin_amdgcn_fdot2(a, b, c, false);
#else
    return c + (float)a.x * (float)b.x + (float)a.y * (float)b.y;
#endif
}

// ---------------------------------------------------------------------------
// Fused dual-layer scan = R12's proven skeleton (split barrier, 1 WG/CU,
// tagged fp32 exchange, parity double-buffer) with the weight paths in fp16:
//   Weff0 AND Weff1 fp16 LDS-resident (64+64 KB -- fp32 couldn't fit both);
//   Win1 streamed fp16 (64 KB/iter vs R12's 256 KB -> off the critical path);
//   matvecs via v_dot2_f32_f16 (2 MAC/instr, fp32 accum) -> compute phases
//   shrink. h stored fp16 in LDS (1 cvt/thread/step); exchange slots, leak
//   state, u0, biases, outputs all stay fp32.
// ---------------------------------------------------------------------------
__launch_bounds__(512, 1)
__global__ void scan2_kernel(const float* __restrict__ Weff0,
                             const float* __restrict__ beff0,
                             const float* __restrict__ Weff1,
                             const float* __restrict__ beff1,
                             const __half* __restrict__ Win1h, // fp16 [H][H]
                             const float* __restrict__ u0,     // (B,S,H)
                             float* __restrict__ out,          // (B,S,H) ys1
                             unsigned long long* __restrict__ hp0,  // [2][B][H]
                             unsigned long long* __restrict__ hp1) {// [2][B][H]
    const int slice = blockIdx.x;   // 0..7
    const int b = blockIdx.y;       // 0..31
    const int tid = threadIdx.x;    // 0..511
    const int c = tid & 31;
    const int hw = tid >> 5;        // 0..15
    const int rloc = hw * 4;
    const int rowbase = slice * 64 + rloc;
    const bool storer = (c == 31);
    const size_t SLOTS = (size_t)BATCH * HDIM;

    __shared__ __align__(16) __half wl0[64 * HDIM];   // 64 KB fp16 Weff0 slice
    __shared__ __align__(16) __half wl1[64 * HDIM];   // 64 KB fp16 Weff1 slice
    __shared__ __align__(16) __half hs0[2][HDIM];     // fp16 h0 (parity)
    __shared__ __align__(16) __half hs1[2][HDIM];     // fp16 h1 (parity)

    // one-time preload + fp32->fp16 convert of both weight slices
    {
        const float4* s0 = reinterpret_cast<const float4*>(
            Weff0 + (size_t)slice * 64 * HDIM);
        const float4* s1 = reinterpret_cast<const float4*>(
            Weff1 + (size_t)slice * 64 * HDIM);
        h2* d0 = reinterpret_cast<h2*>(wl0);
        h2* d1 = reinterpret_cast<h2*>(wl1);
        #pragma unroll
        for (int i = 0; i < 16; ++i) {
            const int idx = tid + 512 * i;
            float4 v = s0[idx];
            h2 a = {(_Float16)v.x, (_Float16)v.y};
            h2 bb = {(_Float16)v.z, (_Float16)v.w};
            d0[2 * idx] = a;  d0[2 * idx + 1] = bb;
            float4 w = s1[idx];
            h2 e = {(_Float16)w.x, (_Float16)w.y};
            h2 f = {(_Float16)w.z, (_Float16)w.w};
            d1[2 * idx] = e;  d1[2 * idx + 1] = f;
        }
    }

    float4 be04 = make_float4(0.f, 0.f, 0.f, 0.f);
    float4 be14 = make_float4(0.f, 0.f, 0.f, 0.f);
    if (storer) {
        be04 = *reinterpret_cast<const float4*>(beff0 + rowbase);
        be14 = *reinterpret_cast<const float4*>(beff1 + rowbase);
    }
    const float lk0 = 0.10f, olk0 = 0.90f;
    const float lk1 = 0.15f, olk1 = 0.85f;
    const float* u0b = u0 + (size_t)b * SEQ * HDIM;
    float* ob = out + (size_t)b * SEQ * HDIM;
    unsigned long long* h0b = hp0 + (size_t)b * HDIM;
    unsigned long long* h1b = hp1 + (size_t)b * HDIM;
    float4 hold0 = make_float4(0.f, 0.f, 0.f, 0.f);
    float4 hold1 = make_float4(0.f, 0.f, 0.f, 0.f);

    __syncthreads();   // weights staged

    for (int i = 0; i <= SEQ; ++i) {
        // stream Win1 rows (fp16, L2-hot, 64KB/WG) -- issue first
        h2 wi[4][4][2];
        #pragma unroll
        for (int r = 0; r < 4; ++r) {
            const h2* wp = reinterpret_cast<const h2*>(
                Win1h + (size_t)(rowbase + r) * HDIM);
            #pragma unroll
            for (int k = 0; k < 4; ++k) {
                const int cq = 2 * (c + 32 * k);
                wi[r][k][0] = wp[cq];
                wi[r][k][1] = wp[cq + 1];
            }
        }
        // u0 prefetch (storer lanes)
        float4 u4 = make_float4(0.f, 0.f, 0.f, 0.f);
        if (storer && i < SEQ)
            u4 = *reinterpret_cast<const float4*>(u0b + (size_t)i * HDIM + rowbase);

        const unsigned long long* sp0 = h0b + (size_t)(i & 1) * SLOTS + tid;
        const unsigned long long* sp1 = h1b + (size_t)((i - 1) & 1) * SLOTS + tid;

        // first-attempt h1 load (finalized after L0)
        unsigned long long v1 = 0ull;
        if (i >= 1) v1 = __hip_atomic_load(sp1, RLX, AGT);

        // poll h0(i): stored early last iteration -> usually ready
        unsigned long long v0 = __hip_atomic_load(sp0, RLX, AGT);
        while ((unsigned)(v0 >> 32) != (unsigned)i)
            v0 = __hip_atomic_load(sp0, RLX, AGT);
        hs0[i & 1][tid] = __float2half(__uint_as_float((unsigned)v0));
        __syncthreads();   // A: hs0 staged

        // ---- L0 step i: a = Weff0_slice . h0(i); EARLY h0(i+1) store ----
        if (i < SEQ) {
            float a0 = 0.f, a1 = 0.f, a2 = 0.f, a3 = 0.f;
            const h2* hv = reinterpret_cast<const h2*>(&hs0[i & 1][0]);
            #pragma unroll
            for (int k = 0; k < 4; ++k) {
                const int cq = 2 * (c + 32 * k);
                h2 ha = hv[cq], hb = hv[cq + 1];
                const h2* w0 = reinterpret_cast<const h2*>(wl0) + (rloc + 0) * 256 + cq;
                const h2* w1 = reinterpret_cast<const h2*>(wl0) + (rloc + 1) * 256 + cq;
                const h2* w2 = reinterpret_cast<const h2*>(wl0) + (rloc + 2) * 256 + cq;
                const h2* w3 = reinterpret_cast<const h2*>(wl0) + (rloc + 3) * 256 + cq;
                a0 = fdot2(w0[0], ha, a0); a0 = fdot2(w0[1], hb, a0);
                a1 = fdot2(w1[0], ha, a1); a1 = fdot2(w1[1], hb, a1);
                a2 = fdot2(w2[0], ha, a2); a2 = fdot2(w2[1], hb, a2);
                a3 = fdot2(w3[0], ha, a3); a3 = fdot2(w3[1], hb, a3);
            }
            a0 = reduce32(a0);
            a1 = reduce32(a1);
            a2 = reduce32(a2);
            a3 = reduce32(a3);
            if (storer) {
                float n0 = olk0 * hold0.x + lk0 * fast_tanh(a0 + u4.x + be04.x);
                float n1 = olk0 * hold0.y + lk0 * fast_tanh(a1 + u4.y + be04.y);
                float n2 = olk0 * hold0.z + lk0 * fast_tanh(a2 + u4.z + be04.z);
                float n3 = olk0 * hold0.w + lk0 * fast_tanh(a3 + u4.w + be04.w);
                hold0 = make_float4(n0, n1, n2, n3);
                unsigned long long tg = ((unsigned long long)(unsigned)(i + 1)) << 32;
                unsigned long long* hp = h0b + (size_t)((i + 1) & 1) * SLOTS + rowbase;
                __hip_atomic_store(hp + 0, tg | __float_as_uint(n0), RLX, AGT);
                __hip_atomic_store(hp + 1, tg | __float_as_uint(n1), RLX, AGT);
                __hip_atomic_store(hp + 2, tg | __float_as_uint(n2), RLX, AGT);
                __hip_atomic_store(hp + 3, tg | __float_as_uint(n3), RLX, AGT);
            }
        }

        if (i >= 1) {
            // finalize h1(i-1) poll (first-try issued at top, pre-L0)
            while ((unsigned)(v1 >> 32) != (unsigned)(i - 1))
                v1 = __hip_atomic_load(sp1, RLX, AGT);
            hs1[(i - 1) & 1][tid] = __float2half(__uint_as_float((unsigned)v1));
        }
        __syncthreads();   // B: hs1 staged

        // ---- L1 step i-1: g = Win1.h0(i) + Weff1.h1(i-1), single reduce ----
        if (i >= 1) {
            float g0 = 0.f, g1 = 0.f, g2 = 0.f, g3 = 0.f;
            const h2* pv = reinterpret_cast<const h2*>(&hs0[i & 1][0]);
            const h2* qv = reinterpret_cast<const h2*>(&hs1[(i - 1) & 1][0]);
            #pragma unroll
            for (int k = 0; k < 4; ++k) {
                const int cq = 2 * (c + 32 * k);
                h2 pa = pv[cq], pb = pv[cq + 1];
                h2 qa = qv[cq], qb = qv[cq + 1];
                const h2* e0 = reinterpret_cast<const h2*>(wl1) + (rloc + 0) * 256 + cq;
                const h2* e1 = reinterpret_cast<const h2*>(wl1) + (rloc + 1) * 256 + cq;
                const h2* e2 = reinterpret_cast<const h2*>(wl1) + (rloc + 2) * 256 + cq;
                const h2* e3 = reinterpret_cast<const h2*>(wl1) + (rloc + 3) * 256 + cq;
                g0 = fdot2(wi[0][k][0], pa, g0); g0 = fdot2(wi[0][k][1], pb, g0);
                g0 = fdot2(e0[0], qa, g0);       g0 = fdot2(e0[1], qb, g0);
                g1 = fdot2(wi[1][k][0], pa, g1); g1 = fdot2(wi[1][k][1], pb, g1);
                g1 = fdot2(e1[0], qa, g1);       g1 = fdot2(e1[1], qb, g1);
                g2 = fdot2(wi[2][k][0], pa, g2); g2 = fdot2(wi[2][k][1], pb, g2);
                g2 = fdot2(e2[0], qa, g2);       g2 = fdot2(e2[1], qb, g2);
                g3 = fdot2(wi[3][k][0], pa, g3); g3 = fdot2(wi[3][k][1], pb, g3);
                g3 = fdot2(e3[0], qa, g3);       g3 = fdot2(e3[1], qb, g3);
            }
            g0 = reduce32(g0);
            g1 = reduce32(g1);
            g2 = reduce32(g2);
            g3 = reduce32(g3);
            if (storer) {
                float m0 = olk1 * hold1.x + lk1 * fast_tanh(g0 + be14.x);
                float m1 = olk1 * hold1.y + lk1 * fast_tanh(g1 + be14.y);
                float m2 = olk1 * hold1.z + lk1 * fast_tanh(g2 + be14.z);
                float m3 = olk1 * hold1.w + lk1 * fast_tanh(g3 + be14.w);
                hold1 = make_float4(m0, m1, m2, m3);
                unsigned long long tg = ((unsigned long long)(unsigned)i) << 32;
                unsigned long long* hp = h1b + (size_t)(i & 1) * SLOTS + rowbase;
                __hip_atomic_store(hp + 0, tg | __float_as_uint(m0), RLX, AGT);
                __hip_atomic_store(hp + 1, tg | __float_as_uint(m1), RLX, AGT);
                __hip_atomic_store(hp + 2, tg | __float_as_uint(m2), RLX, AGT);
                __hip_atomic_store(hp + 3, tg | __float_as_uint(m3), RLX, AGT);
                *reinterpret_cast<float4*>(ob + (size_t)(i - 1) * HDIM + rowbase) =
                    make_float4(m0, m1, m2, m3);   // ys1
            }
        }
    }
}

// ---------------------------------------------------------------------------
extern "C" void kernel_launch(void* const* d_in, const int* in_sizes, int n_in,
                              void* d_out, int out_size, void* d_ws, size_t ws_size,
                              hipStream_t stream) {
    const float* x      = (const float*)d_in[0];
    const int*   edges  = (const int*)d_in[1];
    const float* W_in0  = (const float*)d_in[2];
    const float* W_res0 = (const float*)d_in[3];
    const float* bias0  = (const float*)d_in[4];
    const float* Wp0    = (const float*)d_in[5];
    const float* bp0    = (const float*)d_in[6];
    const float* Wu0    = (const float*)d_in[7];
    const float* bu0    = (const float*)d_in[8];
    const float* W_in1  = (const float*)d_in[9];
    const float* W_res1 = (const float*)d_in[10];
    const float* bias1  = (const float*)d_in[11];
    const float* Wp1    = (const float*)d_in[12];
    const float* bp1    = (const float*)d_in[13];
    const float* Wu1    = (const float*)d_in[14];
    const float* bu1    = (const float*)d_in[15];

    const int* src = edges;
    const int* dst = edges + NEDGES;
    float* out = (float*)d_out;

    // workspace layout
    char* base = (char*)d_ws;
    float* ws_u = (float*)base;                       // u0: 67,108,864
    char* q = base + (size_t)67108864;
    float* AWp = (float*)q;                           // prologue: 2,097,152
    // post-prologue overlay of AWp's region:
    unsigned long long* hp0 = (unsigned long long*)q;             // 262,144
    unsigned long long* hp1 = (unsigned long long*)(q + 262144);  // 262,144
    __half* Win1h = (__half*)(q + 524288);                        // 524,288
    char* p2 = q + 2097152;
    float* Abp   = (float*)p2;                        // 4,096
    float* Weff0 = (float*)(p2 + 4096);               // 1,048,576
    float* Weff1 = (float*)(p2 + 1052672);            // 1,048,576
    float* beff0 = (float*)(p2 + 2101248);            // 2,048
    float* beff1 = (float*)(p2 + 2103296);            // 2,048

    // ---- layer 0 effective weights ----
    hipMemsetAsync(AWp, 0, 2097152, stream);
    hipMemsetAsync(Abp, 0, 4096, stream);
    scatter_awp_kernel<<<NEDGES, 256, 0, stream>>>(Wp0, src, dst, AWp);
    scatter_abp_kernel<<<NEDGES / 256, 256, 0, stream>>>(bp0, src, dst, Abp);
    gemm64<0><<<dim3(8, 8), 256, 0, stream>>>(Wu0, AWp, Weff0, W_res0, 512, 512, 1024);
    beff_kernel<<<1, 512, 0, stream>>>(Wu0, Abp, bias0, bu0, beff0);

    // ---- layer 1 effective weights ----
    hipMemsetAsync(AWp, 0, 2097152, stream);
    hipMemsetAsync(Abp, 0, 4096, stream);
    scatter_awp_kernel<<<NEDGES, 256, 0, stream>>>(Wp1, src, dst, AWp);
    scatter_abp_kernel<<<NEDGES / 256, 256, 0, stream>>>(bp1, src, dst, Abp);
    gemm64<0><<<dim3(8, 8), 256, 0, stream>>>(Wu1, AWp, Weff1, W_res1, 512, 512, 1024);
    beff_kernel<<<1, 512, 0, stream>>>(Wu1, Abp, bias1, bu1, beff1);

    // ---- u0 = x @ W_in0^T ----
    gemm64<1><<<dim3(512 / 64, 32768 / 64), 256, 0, stream>>>(
        x, W_in0, ws_u, nullptr, BATCH * SEQ, HDIM, DIN);

    // ---- AWp dead: zero exchange slots, build fp16 Win1 ----
    hipMemsetAsync(q, 0, 524288, stream);   // hp0 + hp1 (tags 0, h=0)
    tof16_kernel<<<HDIM * HDIM / 1024, 1024, 0, stream>>>(W_in1, Win1h, HDIM * HDIM);

    // ---- fused dual-layer pipelined scan (ys1 straight to d_out) ----
    scan2_kernel<<<dim3(SLICES, BATCH), 512, 0, stream>>>(
        Weff0, beff0, Weff1, beff1, Win1h, ws_u, out, hp0, hp1);
}

// Round 15
// 3378.519 us; speedup vs baseline: 1.2063x; 1.0206x over previous
//
#include <hip/hip_runtime.h>
#include <hip/hip_bf16.h>
#include <hip/hip_fp16.h>
#include <cstddef>
#include <cstdint>

#define HDIM 512
#define NNODES 1024
#define NEDGES 16384
#define BATCH 32
#define SEQ 1024
#define DIN 128
#define SLICES 8
#define PSLOT (BATCH * 256)   // packed slots per parity (2 fp16 per slot)

#define RLX __ATOMIC_RELAXED
#define AGT __HIP_MEMORY_SCOPE_AGENT

typedef _Float16 h2 __attribute__((ext_vector_type(2)));

__device__ __forceinline__ unsigned pk(float a, float b) {
    h2 v = {(_Float16)a, (_Float16)b};
    return __builtin_bit_cast(unsigned, v);
}

// ---------------------------------------------------------------------------
// Prologue: AWp[d][j] = sum_{e: dst_e=d} Wp[src_e][j]
// ---------------------------------------------------------------------------
__global__ void scatter_awp_kernel(const float* __restrict__ Wp,
                                   const int* __restrict__ src,
                                   const int* __restrict__ dst,
                                   float* __restrict__ AWp) {
    int e = blockIdx.x;
    int c = threadIdx.x;
    int s = src[e], d = dst[e];
    atomicAdd(&AWp[d * HDIM + c],       Wp[s * HDIM + c]);
    atomicAdd(&AWp[d * HDIM + 256 + c], Wp[s * HDIM + 256 + c]);
}

__global__ void scatter_abp_kernel(const float* __restrict__ bp,
                                   const int* __restrict__ src,
                                   const int* __restrict__ dst,
                                   float* __restrict__ Abp) {
    int e = blockIdx.x * blockDim.x + threadIdx.x;
    if (e < NEDGES) atomicAdd(&Abp[dst[e]], bp[src[e]]);
}

__global__ void beff_kernel(const float* __restrict__ Wu,
                            const float* __restrict__ Abp,
                            const float* __restrict__ bias,
                            const float* __restrict__ bu,
                            float* __restrict__ beff) {
    int i = threadIdx.x;
    float s = 0.f;
    for (int d = 0; d < NNODES; ++d) s += Wu[i * NNODES + d] * Abp[d];
    beff[i] = bias[i] + bu[i] + s;
}

__global__ void tof16_kernel(const float* __restrict__ in,
                             __half* __restrict__ out, int n) {
    int i = blockIdx.x * blockDim.x + threadIdx.x;
    if (i < n) out[i] = __float2half_rn(in[i]);
}

// ---------------------------------------------------------------------------
// fp32 tiled GEMM (prologue): C = A @ B (+addend); TB==1 -> B is (N x K)
// ---------------------------------------------------------------------------
template <int TB>
__global__ __launch_bounds__(256) void gemm64(const float* __restrict__ A,
                                              const float* __restrict__ B,
                                              float* __restrict__ C,
                                              const float* __restrict__ addend,
                                              int M, int N, int K) {
    const int bn = blockIdx.x, bm = blockIdx.y;
    const int tid = threadIdx.x;
    const int tx = tid & 15, ty = tid >> 4;
    const int m0 = bm * 64, n0 = bn * 64;

    __shared__ float As[16][68];
    __shared__ float Bs[16][68];

    float acc[4][4] = {};

    for (int k0 = 0; k0 < K; k0 += 16) {
        {
            int kk = tid & 15, m = tid >> 4;
            #pragma unroll
            for (int i = 0; i < 4; ++i)
                As[kk][m + 16 * i] = A[(size_t)(m0 + m + 16 * i) * K + k0 + kk];
        }
        if (TB == 0) {
            int n = tid & 63, kk = tid >> 6;
            #pragma unroll
            for (int i = 0; i < 4; ++i)
                Bs[kk + 4 * i][n] = B[(size_t)(k0 + kk + 4 * i) * N + n0 + n];
        } else {
            int kk = tid & 15, n = tid >> 4;
            #pragma unroll
            for (int i = 0; i < 4; ++i)
                Bs[kk][n + 16 * i] = B[(size_t)(n0 + n + 16 * i) * K + k0 + kk];
        }
        __syncthreads();
        #pragma unroll
        for (int kk = 0; kk < 16; ++kk) {
            float4 a4 = *reinterpret_cast<const float4*>(&As[kk][ty * 4]);
            float4 b4 = *reinterpret_cast<const float4*>(&Bs[kk][tx * 4]);
            float av[4] = {a4.x, a4.y, a4.z, a4.w};
            float bv[4] = {b4.x, b4.y, b4.z, b4.w};
            #pragma unroll
            for (int i = 0; i < 4; ++i)
                #pragma unroll
                for (int j = 0; j < 4; ++j)
                    acc[i][j] += av[i] * bv[j];
        }
        __syncthreads();
    }
    #pragma unroll
    for (int i = 0; i < 4; ++i) {
        int m = m0 + ty * 4 + i;
        #pragma unroll
        for (int j = 0; j < 4; ++j) {
            int n = n0 + tx * 4 + j;
            float v = acc[i][j];
            if (addend) v += addend[(size_t)m * N + n];
            C[(size_t)m * N + n] = v;
        }
    }
}

// ---------------------------------------------------------------------------
// DPP half-wave sum (R5-verified): lanes 31/63 hold their 32-lane half sums.
// ---------------------------------------------------------------------------
template <int CTRL, int RMASK, bool BC>
__device__ __forceinline__ float dpp_add(float x) {
    int t = __builtin_amdgcn_update_dpp(0, __float_as_int(x), CTRL, RMASK, 0xf, BC);
    return x + __int_as_float(t);
}

__device__ __forceinline__ float reduce32(float x) {
    x = dpp_add<0x111, 0xf, true>(x);
    x = dpp_add<0x112, 0xf, true>(x);
    x = dpp_add<0x114, 0xf, true>(x);
    x = dpp_add<0x118, 0xf, true>(x);
    x = dpp_add<0x142, 0xa, false>(x);
    return x;
}

__device__ __forceinline__ float fast_tanh(float x) {
    float e = __expf(2.0f * x);
    return 1.0f - 2.0f / (e + 1.0f);
}

// v_dot2_f32_f16: 2 fp16 MACs with fp32 accumulate (fallback: cvt + fma)
__device__ __forceinline__ float fdot2(h2 a, h2 b, float c) {
#if __has_builtin(__builtin_amdgcn_fdot2)
    return __builtin_amdgcn_fdot2(a, b, c, false);
#else
    return c + (float)a.x * (float)b.x + (float)a.y * (float)b.y;
#endif
}

// ---------------------------------------------------------------------------
// Fused dual-layer scan = R14 skeleton + exchange-level optimizations:
//  (1) packed fp16 exchange: slot = (tag32, 2xfp16). Numerically identical to
//      R14 (consumers used fp16 h already); stores 64->32, polls 512->256 per
//      batch-layer-step -> straggler tail + IC contention drop.
//  (2) L1 matvec split around the h1 finalize: part1 Win1.h0(i) needs no h1
//      and runs BEFORE the finalize; part2 Weff1.h1 accumulates into the same
//      registers after barrier B (single reduce). h1 chain constraint falls
//      from RTT+L1 to RTT+part2.
//  (3) two-outstanding-load spin (v/vb rotate): halves poll-detect quantum.
// Slot-reuse safety: unchanged monotonic-tag induction (tag t+2 stored only
// after producer polled t+1 from all peers, which happens only after every
// peer's poll of t passed its following barrier).
// ---------------------------------------------------------------------------
__launch_bounds__(512, 1)
__global__ void scan2_kernel(const float* __restrict__ Weff0,
                             const float* __restrict__ beff0,
                             const float* __restrict__ Weff1,
                             const float* __restrict__ beff1,
                             const __half* __restrict__ Win1h, // fp16 [H][H]
                             const float* __restrict__ u0,     // (B,S,H)
                             float* __restrict__ out,          // (B,S,H) ys1
                             unsigned long long* __restrict__ hp0,  // [2][B][256]
                             unsigned long long* __restrict__ hp1) {// [2][B][256]
    const int slice = blockIdx.x;   // 0..7
    const int b = blockIdx.y;       // 0..31
    const int tid = threadIdx.x;    // 0..511
    const int c = tid & 31;
    const int hw = tid >> 5;        // 0..15
    const int rloc = hw * 4;
    const int rowbase = slice * 64 + rloc;
    const bool storer = (c == 31);
    const bool poller = (tid < 256);

    __shared__ __align__(16) __half wl0[64 * HDIM];   // 64 KB fp16 Weff0 slice
    __shared__ __align__(16) __half wl1[64 * HDIM];   // 64 KB fp16 Weff1 slice
    __shared__ __align__(16) __half hs0[2][HDIM];     // fp16 h0 (parity)
    __shared__ __align__(16) __half hs1[2][HDIM];     // fp16 h1 (parity)

    // one-time preload + fp32->fp16 convert of both weight slices
    {
        const float4* s0 = reinterpret_cast<const float4*>(
            Weff0 + (size_t)slice * 64 * HDIM);
        const float4* s1 = reinterpret_cast<const float4*>(
            Weff1 + (size_t)slice * 64 * HDIM);
        h2* d0 = reinterpret_cast<h2*>(wl0);
        h2* d1 = reinterpret_cast<h2*>(wl1);
        #pragma unroll
        for (int i = 0; i < 16; ++i) {
            const int idx = tid + 512 * i;
            float4 v = s0[idx];
            d0[2 * idx]     = h2{(_Float16)v.x, (_Float16)v.y};
            d0[2 * idx + 1] = h2{(_Float16)v.z, (_Float16)v.w};
            float4 w = s1[idx];
            d1[2 * idx]     = h2{(_Float16)w.x, (_Float16)w.y};
            d1[2 * idx + 1] = h2{(_Float16)w.z, (_Float16)w.w};
        }
    }

    float4 be04 = make_float4(0.f, 0.f, 0.f, 0.f);
    float4 be14 = make_float4(0.f, 0.f, 0.f, 0.f);
    if (storer) {
        be04 = *reinterpret_cast<const float4*>(beff0 + rowbase);
        be14 = *reinterpret_cast<const float4*>(beff1 + rowbase);
    }
    const float lk0 = 0.10f, olk0 = 0.90f;
    const float lk1 = 0.15f, olk1 = 0.85f;
    const float* u0b = u0 + (size_t)b * SEQ * HDIM;
    float* ob = out + (size_t)b * SEQ * HDIM;
    unsigned long long* h0b = hp0 + (size_t)b * 256;
    unsigned long long* h1b = hp1 + (size_t)b * 256;
    const int pslot = slice * 32 + hw * 2;   // storer's packed slot base
    float4 hold0 = make_float4(0.f, 0.f, 0.f, 0.f);
    float4 hold1 = make_float4(0.f, 0.f, 0.f, 0.f);

    __syncthreads();   // weights staged

    for (int i = 0; i <= SEQ; ++i) {
        // stream Win1 rows (fp16, L2-hot, 64KB/WG) -- issue first
        h2 wi[4][4][2];
        #pragma unroll
        for (int r = 0; r < 4; ++r) {
            const h2* wp = reinterpret_cast<const h2*>(
                Win1h + (size_t)(rowbase + r) * HDIM);
            #pragma unroll
            for (int k = 0; k < 4; ++k) {
                const int cq = 2 * (c + 32 * k);
                wi[r][k][0] = wp[cq];
                wi[r][k][1] = wp[cq + 1];
            }
        }
        // u0 prefetch (storer lanes)
        float4 u4 = make_float4(0.f, 0.f, 0.f, 0.f);
        if (storer && i < SEQ)
            u4 = *reinterpret_cast<const float4*>(u0b + (size_t)i * HDIM + rowbase);

        const unsigned long long* sp0 = h0b + (size_t)(i & 1) * PSLOT + tid;
        const unsigned long long* sp1 = h1b + (size_t)((i - 1) & 1) * PSLOT + tid;

        // first-attempt h1 load (finalized after L0 + part1)
        unsigned long long v1 = 0ull;
        if (poller && i >= 1) v1 = __hip_atomic_load(sp1, RLX, AGT);

        // poll h0(i): two-outstanding-load spin
        if (poller) {
            unsigned long long v0 = __hip_atomic_load(sp0, RLX, AGT);
            unsigned long long vb = __hip_atomic_load(sp0, RLX, AGT);
            while ((unsigned)(v0 >> 32) != (unsigned)i) {
                v0 = vb;
                vb = __hip_atomic_load(sp0, RLX, AGT);
            }
            reinterpret_cast<h2*>(&hs0[i & 1][0])[tid] =
                __builtin_bit_cast(h2, (unsigned)v0);
        }
        __syncthreads();   // A: hs0 staged

        // ---- L0 step i: a = Weff0_slice . h0(i); EARLY h0(i+1) store ----
        if (i < SEQ) {
            float a0 = 0.f, a1 = 0.f, a2 = 0.f, a3 = 0.f;
            const h2* hv = reinterpret_cast<const h2*>(&hs0[i & 1][0]);
            #pragma unroll
            for (int k = 0; k < 4; ++k) {
                const int cq = 2 * (c + 32 * k);
                h2 ha = hv[cq], hb = hv[cq + 1];
                const h2* w0 = reinterpret_cast<const h2*>(wl0) + (rloc + 0) * 256 + cq;
                const h2* w1 = reinterpret_cast<const h2*>(wl0) + (rloc + 1) * 256 + cq;
                const h2* w2 = reinterpret_cast<const h2*>(wl0) + (rloc + 2) * 256 + cq;
                const h2* w3 = reinterpret_cast<const h2*>(wl0) + (rloc + 3) * 256 + cq;
                a0 = fdot2(w0[0], ha, a0); a0 = fdot2(w0[1], hb, a0);
                a1 = fdot2(w1[0], ha, a1); a1 = fdot2(w1[1], hb, a1);
                a2 = fdot2(w2[0], ha, a2); a2 = fdot2(w2[1], hb, a2);
                a3 = fdot2(w3[0], ha, a3); a3 = fdot2(w3[1], hb, a3);
            }
            a0 = reduce32(a0);
            a1 = reduce32(a1);
            a2 = reduce32(a2);
            a3 = reduce32(a3);
            if (storer) {
                float n0 = olk0 * hold0.x + lk0 * fast_tanh(a0 + u4.x + be04.x);
                float n1 = olk0 * hold0.y + lk0 * fast_tanh(a1 + u4.y + be04.y);
                float n2 = olk0 * hold0.z + lk0 * fast_tanh(a2 + u4.z + be04.z);
                float n3 = olk0 * hold0.w + lk0 * fast_tanh(a3 + u4.w + be04.w);
                hold0 = make_float4(n0, n1, n2, n3);
                unsigned long long tg = ((unsigned long long)(unsigned)(i + 1)) << 32;
                unsigned long long* hp = h0b + (size_t)((i + 1) & 1) * PSLOT + pslot;
                __hip_atomic_store(hp + 0, tg | pk(n0, n1), RLX, AGT);
                __hip_atomic_store(hp + 1, tg | pk(n2, n3), RLX, AGT);
            }
        }

        // ---- L1 part 1: g += Win1 . h0(i)  (no h1 dependence) ----
        float g0 = 0.f, g1 = 0.f, g2 = 0.f, g3 = 0.f;
        if (i >= 1) {
            const h2* pv = reinterpret_cast<const h2*>(&hs0[i & 1][0]);
            #pragma unroll
            for (int k = 0; k < 4; ++k) {
                const int cq = 2 * (c + 32 * k);
                h2 pa = pv[cq], pb = pv[cq + 1];
                g0 = fdot2(wi[0][k][0], pa, g0); g0 = fdot2(wi[0][k][1], pb, g0);
                g1 = fdot2(wi[1][k][0], pa, g1); g1 = fdot2(wi[1][k][1], pb, g1);
                g2 = fdot2(wi[2][k][0], pa, g2); g2 = fdot2(wi[2][k][1], pb, g2);
                g3 = fdot2(wi[3][k][0], pa, g3); g3 = fdot2(wi[3][k][1], pb, g3);
            }
            // finalize h1(i-1) poll (first-try issued at top; two-load spin)
            if (poller) {
                unsigned long long vb = __hip_atomic_load(sp1, RLX, AGT);
                while ((unsigned)(v1 >> 32) != (unsigned)(i - 1)) {
                    v1 = vb;
                    vb = __hip_atomic_load(sp1, RLX, AGT);
                }
                reinterpret_cast<h2*>(&hs1[(i - 1) & 1][0])[tid] =
                    __builtin_bit_cast(h2, (unsigned)v1);
            }
        }
        __syncthreads();   // B: hs1 staged

        // ---- L1 part 2: g += Weff1 . h1(i-1); reduce; store ----
        if (i >= 1) {
            const h2* qv = reinterpret_cast<const h2*>(&hs1[(i - 1) & 1][0]);
            #pragma unroll
            for (int k = 0; k < 4; ++k) {
                const int cq = 2 * (c + 32 * k);
                h2 qa = qv[cq], qb = qv[cq + 1];
                const h2* e0 = reinterpret_cast<const h2*>(wl1) + (rloc + 0) * 256 + cq;
                const h2* e1 = reinterpret_cast<const h2*>(wl1) + (rloc + 1) * 256 + cq;
                const h2* e2 = reinterpret_cast<const h2*>(wl1) + (rloc + 2) * 256 + cq;
                const h2* e3 = reinterpret_cast<const h2*>(wl1) + (rloc + 3) * 256 + cq;
                g0 = fdot2(e0[0], qa, g0); g0 = fdot2(e0[1], qb, g0);
                g1 = fdot2(e1[0], qa, g1); g1 = fdot2(e1[1], qb, g1);
                g2 = fdot2(e2[0], qa, g2); g2 = fdot2(e2[1], qb, g2);
                g3 = fdot2(e3[0], qa, g3); g3 = fdot2(e3[1], qb, g3);
            }
            g0 = reduce32(g0);
            g1 = reduce32(g1);
            g2 = reduce32(g2);
            g3 = reduce32(g3);
            if (storer) {
                float m0 = olk1 * hold1.x + lk1 * fast_tanh(g0 + be14.x);
                float m1 = olk1 * hold1.y + lk1 * fast_tanh(g1 + be14.y);
                float m2 = olk1 * hold1.z + lk1 * fast_tanh(g2 + be14.z);
                float m3 = olk1 * hold1.w + lk1 * fast_tanh(g3 + be14.w);
                hold1 = make_float4(m0, m1, m2, m3);
                unsigned long long tg = ((unsigned long long)(unsigned)i) << 32;
                unsigned long long* hp = h1b + (size_t)(i & 1) * PSLOT + pslot;
                __hip_atomic_store(hp + 0, tg | pk(m0, m1), RLX, AGT);
                __hip_atomic_store(hp + 1, tg | pk(m2, m3), RLX, AGT);
                *reinterpret_cast<float4*>(ob + (size_t)(i - 1) * HDIM + rowbase) =
                    make_float4(m0, m1, m2, m3);   // ys1
            }
        }
    }
}

// ---------------------------------------------------------------------------
extern "C" void kernel_launch(void* const* d_in, const int* in_sizes, int n_in,
                              void* d_out, int out_size, void* d_ws, size_t ws_size,
                              hipStream_t stream) {
    const float* x      = (const float*)d_in[0];
    const int*   edges  = (const int*)d_in[1];
    const float* W_in0  = (const float*)d_in[2];
    const float* W_res0 = (const float*)d_in[3];
    const float* bias0  = (const float*)d_in[4];
    const float* Wp0    = (const float*)d_in[5];
    const float* bp0    = (const float*)d_in[6];
    const float* Wu0    = (const float*)d_in[7];
    const float* bu0    = (const float*)d_in[8];
    const float* W_in1  = (const float*)d_in[9];
    const float* W_res1 = (const float*)d_in[10];
    const float* bias1  = (const float*)d_in[11];
    const float* Wp1    = (const float*)d_in[12];
    const float* bp1    = (const float*)d_in[13];
    const float* Wu1    = (const float*)d_in[14];
    const float* bu1    = (const float*)d_in[15];

    const int* src = edges;
    const int* dst = edges + NEDGES;
    float* out = (float*)d_out;

    // workspace layout
    char* base = (char*)d_ws;
    float* ws_u = (float*)base;                       // u0: 67,108,864
    char* q = base + (size_t)67108864;
    float* AWp = (float*)q;                           // prologue: 2,097,152
    // post-prologue overlay of AWp's region:
    unsigned long long* hp0 = (unsigned long long*)q;             // 131,072
    unsigned long long* hp1 = (unsigned long long*)(q + 131072);  // 131,072
    __half* Win1h = (__half*)(q + 262144);                        // 524,288
    char* p2 = q + 2097152;
    float* Abp   = (float*)p2;                        // 4,096
    float* Weff0 = (float*)(p2 + 4096);               // 1,048,576
    float* Weff1 = (float*)(p2 + 1052672);            // 1,048,576
    float* beff0 = (float*)(p2 + 2101248);            // 2,048
    float* beff1 = (float*)(p2 + 2103296);            // 2,048

    // ---- layer 0 effective weights ----
    hipMemsetAsync(AWp, 0, 2097152, stream);
    hipMemsetAsync(Abp, 0, 4096, stream);
    scatter_awp_kernel<<<NEDGES, 256, 0, stream>>>(Wp0, src, dst, AWp);
    scatter_abp_kernel<<<NEDGES / 256, 256, 0, stream>>>(bp0, src, dst, Abp);
    gemm64<0><<<dim3(8, 8), 256, 0, stream>>>(Wu0, AWp, Weff0, W_res0, 512, 512, 1024);
    beff_kernel<<<1, 512, 0, stream>>>(Wu0, Abp, bias0, bu0, beff0);

    // ---- layer 1 effective weights ----
    hipMemsetAsync(AWp, 0, 2097152, stream);
    hipMemsetAsync(Abp, 0, 4096, stream);
    scatter_awp_kernel<<<NEDGES, 256, 0, stream>>>(Wp1, src, dst, AWp);
    scatter_abp_kernel<<<NEDGES / 256, 256, 0, stream>>>(bp1, src, dst, Abp);
    gemm64<0><<<dim3(8, 8), 256, 0, stream>>>(Wu1, AWp, Weff1, W_res1, 512, 512, 1024);
    beff_kernel<<<1, 512, 0, stream>>>(Wu1, Abp, bias1, bu1, beff1);

    // ---- u0 = x @ W_in0^T ----
    gemm64<1><<<dim3(512 / 64, 32768 / 64), 256, 0, stream>>>(
        x, W_in0, ws_u, nullptr, BATCH * SEQ, HDIM, DIN);

    // ---- AWp dead: zero exchange slots, build fp16 Win1 ----
    hipMemsetAsync(q, 0, 262144, stream);   // hp0 + hp1 (tags 0, h=0)
    tof16_kernel<<<HDIM * HDIM / 1024, 1024, 0, stream>>>(W_in1, Win1h, HDIM * HDIM);

    // ---- fused dual-layer pipelined scan (ys1 straight to d_out) ----
    scan2_kernel<<<dim3(SLICES, BATCH), 512, 0, stream>>>(
        Weff0, beff0, Weff1, beff1, Win1h, ws_u, out, hp0, hp1);
}